// Round 1
// baseline (2200.564 us; speedup 1.0000x reference)
//
#include <hip/hip_runtime.h>

// Problem constants
constexpr int Bc = 32, Nc = 2048, Fc = 64, Tc = 24;

// ---------- helpers ----------
__device__ __forceinline__ unsigned short f2bf(float f) {
  unsigned u = __float_as_uint(f);
  u += 0x7fffu + ((u >> 16) & 1u);   // round-to-nearest-even
  return (unsigned short)(u >> 16);
}

#define AS1(p) ((const __attribute__((address_space(1))) unsigned int*)(p))
#define AS3(p) ((__attribute__((address_space(3))) unsigned int*)(p))

typedef __attribute__((ext_vector_type(8))) short bfrag;   // 8 bf16 (4 VGPRs)
typedef __attribute__((ext_vector_type(4))) float ffrag;   // 4 fp32 acc

// ---------- Kernel A: x -> lhs[b,n,t], rhsT[b,m,t] ----------
// lhs[b,n,t]  = sum_f (sum_t' x[b,n,f,t']*W1[t']) * W2[f,t]
// rhsT[b,m,t] = sum_f W3[f]*x[b,m,f,t]
__global__ __launch_bounds__(256) void kA(const float* __restrict__ x,
                                          const float* __restrict__ W1,
                                          const float* __restrict__ W2,
                                          const float* __restrict__ W3,
                                          float* __restrict__ lhs,
                                          float* __restrict__ rhsT) {
  __shared__ float W2s[Fc * Tc];      // 64x24
  __shared__ float xs[4][Fc][26];     // pad 24->26: breaks stride-24 bank aliasing
  __shared__ float tmp[4][Fc];
  const int tid = threadIdx.x;
  for (int i = tid; i < Fc * Tc; i += 256) W2s[i] = W2[i];
  const int wave = tid >> 6, lane = tid & 63;
  const size_t pair = (size_t)blockIdx.x * 4 + wave;   // pair = b*N + n
  const float* xp = x + pair * (size_t)(Fc * Tc);
  // stage 1536 floats coalesced as 768 float2
#pragma unroll
  for (int s = 0; s < 12; ++s) {
    int f2 = lane + 64 * s;           // 0..767
    int row = f2 / 12, c2 = (f2 % 12) * 2;
    float2 v = *(const float2*)(xp + (size_t)f2 * 2);
    xs[wave][row][c2] = v.x;
    xs[wave][row][c2 + 1] = v.y;
  }
  __syncthreads();
  {
    const int f = lane;
    float acc = 0.f;
#pragma unroll
    for (int t = 0; t < Tc; ++t) acc += xs[wave][f][t] * W1[t];
    tmp[wave][f] = acc;
  }
  __syncthreads();
  if (lane < 48) {
    const int t = lane >> 1, h = lane & 1;
    const int f0 = h * 32;
    float lacc = 0.f, racc = 0.f;
#pragma unroll
    for (int i = 0; i < 32; ++i) {
      int f = f0 + i;
      lacc += tmp[wave][f] * W2s[f * Tc + t];
      racc += W3[f] * xs[wave][f][t];
    }
    lacc += __shfl_xor(lacc, 1);
    racc += __shfl_xor(racc, 1);
    if (h == 0) {
      lhs[pair * Tc + t] = lacc;
      rhsT[pair * Tc + t] = racc;
    }
  }
}

// ---------- Kernel V: Vs fp32 -> bf16 ----------
__global__ __launch_bounds__(256) void kVs(const float* __restrict__ Vs,
                                           unsigned short* __restrict__ Vb) {
  size_t i = ((size_t)blockIdx.x * 256 + threadIdx.x) * 4;
  float4 v = *(const float4*)(Vs + i);
  ushort4 o;
  o.x = f2bf(v.x); o.y = f2bf(v.y); o.z = f2bf(v.z); o.w = f2bf(v.w);
  *(ushort4*)(Vb + i) = o;
}

// ---------- Kernel P: sigT[b][m][k] = sigmoid(lhs[b,k,:].rhsT[b,m,:] + bs[k,m]) ----------
__global__ __launch_bounds__(256) void kP(const float* __restrict__ lhs,
                                          const float* __restrict__ rhsT,
                                          const float* __restrict__ bsr,
                                          unsigned short* __restrict__ sigT) {
  __shared__ float Lt[Tc][132];   // transposed tiles, pad 128->132 (b128-aligned)
  __shared__ float Rt[Tc][132];
  const int b = blockIdx.z;
  const int i0 = blockIdx.y * 128;   // product row range (k of S-GEMM)
  const int j0 = blockIdx.x * 128;   // product col range (m)
  const int tid = threadIdx.x;
  const float* lp = lhs + ((size_t)b * Nc + i0) * Tc;
  const float* rp = rhsT + ((size_t)b * Nc + j0) * Tc;
#pragma unroll
  for (int s = 0; s < 6; ++s) {
    int f2 = tid + 256 * s;                 // 0..1535
    int row = f2 / 12, c2 = (f2 % 12) * 2;
    float2 v = *(const float2*)(lp + (size_t)row * Tc + c2);
    Lt[c2][row] = v.x; Lt[c2 + 1][row] = v.y;
    float2 w = *(const float2*)(rp + (size_t)row * Tc + c2);
    Rt[c2][row] = w.x; Rt[c2 + 1][row] = w.y;
  }
  __syncthreads();
  const int tx = tid & 15, ty = tid >> 4;
  const int ri = ty * 8, cj = tx * 8;
  float acc[8][8];
#pragma unroll
  for (int a = 0; a < 8; ++a) {   // init with bs tile
    const float* bp = bsr + (size_t)(i0 + ri + a) * Nc + j0 + cj;
    float4 b0 = *(const float4*)bp;
    float4 b1 = *(const float4*)(bp + 4);
    acc[a][0] = b0.x; acc[a][1] = b0.y; acc[a][2] = b0.z; acc[a][3] = b0.w;
    acc[a][4] = b1.x; acc[a][5] = b1.y; acc[a][6] = b1.z; acc[a][7] = b1.w;
  }
#pragma unroll
  for (int t = 0; t < Tc; ++t) {
    float la[8], ra[8];
    *(float4*)&la[0] = *(const float4*)&Lt[t][ri];
    *(float4*)&la[4] = *(const float4*)&Lt[t][ri + 4];
    *(float4*)&ra[0] = *(const float4*)&Rt[t][cj];
    *(float4*)&ra[4] = *(const float4*)&Rt[t][cj + 4];
#pragma unroll
    for (int a = 0; a < 8; ++a)
#pragma unroll
      for (int c = 0; c < 8; ++c) acc[a][c] += la[a] * ra[c];
  }
#pragma unroll
  for (int c = 0; c < 8; ++c) {
    unsigned short o[8];
#pragma unroll
    for (int a = 0; a < 8; ++a) {
      float e = __expf(-acc[a][c]);
      o[a] = f2bf(__fdividef(1.0f, 1.0f + e));
    }
    uint4 pk;
    pk.x = (unsigned)o[0] | ((unsigned)o[1] << 16);
    pk.y = (unsigned)o[2] | ((unsigned)o[3] << 16);
    pk.z = (unsigned)o[4] | ((unsigned)o[5] << 16);
    pk.w = (unsigned)o[6] | ((unsigned)o[7] << 16);
    *(uint4*)(sigT + ((size_t)b * Nc + j0 + cj + c) * Nc + i0 + ri) = pk;
  }
}

// ---------- Kernel G: S[b] = Vs_bf16 (N,N) @ sig_bf16[b] (N,N), fp32 out ----------
// m97 structure: 128x128 tile, BK=32, global_load_lds 16B, 16x16x32 MFMA.
__global__ __launch_bounds__(256) void kG(const unsigned short* __restrict__ A,
                                          const unsigned short* __restrict__ Bm,
                                          float* __restrict__ S) {
  __shared__ unsigned short As[128 * 32];   // [n-row][k] row-major
  __shared__ unsigned short Bs[128 * 32];   // [m-row][k] row-major (B pre-transposed)
  const int b = blockIdx.y;
  const int n0 = (blockIdx.x >> 4) << 7;
  const int m0 = (blockIdx.x & 15) << 7;
  const int tid = threadIdx.x;
  const int wave = tid >> 6, lane = tid & 63;
  const int quad = lane >> 4, l16 = lane & 15;
  const int wrow = (wave >> 1) << 6, wcol = (wave & 1) << 6;
  const unsigned short* Bg = Bm + (size_t)b * Nc * Nc;

  ffrag acc[4][4];
#pragma unroll
  for (int i = 0; i < 4; ++i)
#pragma unroll
    for (int j = 0; j < 4; ++j) acc[i][j] = (ffrag){0.f, 0.f, 0.f, 0.f};

  const int part = (lane & 3) * 8;              // k sub-offset of 16B chunk
  const int row0 = (wave << 4) + (lane >> 2);   // rows 0..63   (round 0)
  const int row1 = row0 + 64;                   // rows 64..127 (round 1)

  for (int kt = 0; kt < Nc / 32; ++kt) {
    const int k0 = kt * 32;
    __builtin_amdgcn_global_load_lds(AS1(A + (size_t)(n0 + row0) * Nc + k0 + part),
                                     AS3(&As[(wave * 64) * 8]), 16, 0, 0);
    __builtin_amdgcn_global_load_lds(AS1(A + (size_t)(n0 + row1) * Nc + k0 + part),
                                     AS3(&As[(256 + wave * 64) * 8]), 16, 0, 0);
    __builtin_amdgcn_global_load_lds(AS1(Bg + (size_t)(m0 + row0) * Nc + k0 + part),
                                     AS3(&Bs[(wave * 64) * 8]), 16, 0, 0);
    __builtin_amdgcn_global_load_lds(AS1(Bg + (size_t)(m0 + row1) * Nc + k0 + part),
                                     AS3(&Bs[(256 + wave * 64) * 8]), 16, 0, 0);
    __syncthreads();   // drains vmcnt (compiler emits full waitcnt before barrier)
    bfrag af[4], bg[4];
#pragma unroll
    for (int mi = 0; mi < 4; ++mi)
      af[mi] = *(const bfrag*)&As[(wrow + mi * 16 + l16) * 32 + quad * 8];
#pragma unroll
    for (int ni = 0; ni < 4; ++ni)
      bg[ni] = *(const bfrag*)&Bs[(wcol + ni * 16 + l16) * 32 + quad * 8];
#pragma unroll
    for (int mi = 0; mi < 4; ++mi)
#pragma unroll
      for (int ni = 0; ni < 4; ++ni)
        acc[mi][ni] = __builtin_amdgcn_mfma_f32_16x16x32_bf16(af[mi], bg[ni], acc[mi][ni], 0, 0, 0);
    __syncthreads();
  }
  float* Sp = S + (size_t)b * Nc * Nc;
#pragma unroll
  for (int mi = 0; mi < 4; ++mi)
#pragma unroll
    for (int r = 0; r < 4; ++r) {
      const int row = n0 + wrow + mi * 16 + quad * 4 + r;
#pragma unroll
      for (int ni = 0; ni < 4; ++ni)
        Sp[(size_t)row * Nc + (m0 + wcol + ni * 16 + l16)] = acc[mi][ni][r];
    }
}

// ---------- Softmax over axis 1 (columns), in-place on S ----------
__global__ __launch_bounds__(256) void kS1(const float* __restrict__ S,
                                           float* __restrict__ pmax,
                                           float* __restrict__ psum) {
  const int b = blockIdx.z, mt = blockIdx.y, nc = blockIdx.x;
  const int m = mt * 256 + threadIdx.x;
  const float* col = S + (size_t)b * Nc * Nc + m;
  float mx = -3.0e38f, sm = 0.f;
  const int ns = nc * 512;
#pragma unroll 4
  for (int n = ns; n < ns + 512; ++n) {
    float v = col[(size_t)n * Nc];
    float nm = fmaxf(mx, v);
    sm = sm * __expf(mx - nm) + __expf(v - nm);
    mx = nm;
  }
  pmax[(size_t)(b * 4 + nc) * Nc + m] = mx;
  psum[(size_t)(b * 4 + nc) * Nc + m] = sm;
}

__global__ __launch_bounds__(256) void kS1b(const float* __restrict__ pmax,
                                            const float* __restrict__ psum,
                                            float* __restrict__ rmax,
                                            float* __restrict__ rinv) {
  const int i = blockIdx.x * 256 + threadIdx.x;   // b*Nc + m
  const int b = i >> 11, m = i & 2047;
  const float* pm = pmax + (size_t)b * 4 * Nc + m;
  const float* ps = psum + (size_t)b * 4 * Nc + m;
  float gm = pm[0];
#pragma unroll
  for (int c = 1; c < 4; ++c) gm = fmaxf(gm, pm[(size_t)c * Nc]);
  float gs = 0.f;
#pragma unroll
  for (int c = 0; c < 4; ++c) gs += ps[(size_t)c * Nc] * __expf(pm[(size_t)c * Nc] - gm);
  rmax[i] = gm;
  rinv[i] = 1.0f / gs;
}

__global__ __launch_bounds__(256) void kS2(float* __restrict__ S,
                                           const float* __restrict__ rmax,
                                           const float* __restrict__ rinv) {
  const int b = blockIdx.z, mt = blockIdx.y, nc = blockIdx.x;
  const int m = mt * 256 + threadIdx.x;
  const float gm = rmax[b * Nc + m];
  const float iv = rinv[b * Nc + m];
  float* col = S + (size_t)b * Nc * Nc + m;
  const int ns = nc * 256;
#pragma unroll 4
  for (int n = ns; n < ns + 256; ++n) {
    float v = col[(size_t)n * Nc];
    col[(size_t)n * Nc] = __expf(v - gm) * iv;
  }
}

// ---------- launch ----------
extern "C" void kernel_launch(void* const* d_in, const int* in_sizes, int n_in,
                              void* d_out, int out_size, void* d_ws, size_t ws_size,
                              hipStream_t stream) {
  const float* x   = (const float*)d_in[0];
  const float* W1  = (const float*)d_in[1];
  const float* W2  = (const float*)d_in[2];
  const float* W3  = (const float*)d_in[3];
  const float* bsr = (const float*)d_in[4];
  const float* Vs  = (const float*)d_in[5];
  float* out = (float*)d_out;

  // workspace layout (total 292,028,416 B)
  char* ws = (char*)d_ws;
  constexpr size_t SIGT_B = (size_t)Bc * Nc * Nc * 2;     // 268,435,456
  constexpr size_t VB_B   = (size_t)Nc * Nc * 2;          //   8,388,608
  constexpr size_t LHS_B  = (size_t)Bc * Nc * Tc * 4;     //   6,291,456
  constexpr size_t PM_B   = (size_t)Bc * 4 * Nc * 4;      //   1,048,576
  unsigned short* sigT = (unsigned short*)ws;
  unsigned short* Vb   = (unsigned short*)(ws + SIGT_B);
  float* lhs  = (float*)(ws + SIGT_B + VB_B);
  float* rhsT = (float*)(ws + SIGT_B + VB_B + LHS_B);
  float* pmax = (float*)(ws + SIGT_B + VB_B + 2 * LHS_B);
  float* psum = (float*)(ws + SIGT_B + VB_B + 2 * LHS_B + PM_B);
  float* rmax = (float*)(ws + SIGT_B + VB_B + 2 * LHS_B + 2 * PM_B);
  float* rinv = (float*)(ws + SIGT_B + VB_B + 2 * LHS_B + 2 * PM_B + (size_t)Bc * Nc * 4);

  kA<<<Bc * Nc / 4, 256, 0, stream>>>(x, W1, W2, W3, lhs, rhsT);
  kVs<<<(Nc * Nc) / 1024, 256, 0, stream>>>(Vs, Vb);
  kP<<<dim3(Nc / 128, Nc / 128, Bc), 256, 0, stream>>>(lhs, rhsT, bsr, sigT);
  kG<<<dim3((Nc / 128) * (Nc / 128), Bc), 256, 0, stream>>>(Vb, sigT, out);
  kS1<<<dim3(4, Nc / 256, Bc), 256, 0, stream>>>(out, pmax, psum);
  kS1b<<<Bc * Nc / 256, 256, 0, stream>>>(pmax, psum, rmax, rinv);
  kS2<<<dim3(Nc / 256, Nc / 256, Bc), 256, 0, stream>>>(out, rmax, rinv);
}